// Round 4
// baseline (129.609 us; speedup 1.0000x reference)
//
#include <hip/hip_runtime.h>

// DSAttention flash kernel, round 3: split-K (flash-decoding).
// Each (b,h,qtile) is split into key-chunks of CH=8 tiles (512 keys); chunks
// compute partial (O', m, l) -> workspace; a combine kernel merges them.
// Single-chunk qtiles write directly. Fallback to monolithic (CH=32) if
// ws_size is too small. Keeps r2 machinery: MFMA rowsum-ones trick, DPP max,
// packed P/V LDS writes, double-buffered staging with register prefetch.

typedef _Float16 h8 __attribute__((ext_vector_type(8)));
typedef _Float16 h2 __attribute__((ext_vector_type(2)));
typedef float f32x4 __attribute__((ext_vector_type(4)));

constexpr int Bc = 2, Lc = 2048, Hc = 8, Ec = 64, Sc = 2048;
constexpr int QT = 64, KT = 64;
constexpr int NQT = Lc / QT;          // 32 q-tiles
constexpr int LDK = 72;               // LDS row stride (halfs)
constexpr float SCALE = 0.125f;
constexpr float LOG2E = 1.44269504088896340736f;

__device__ __forceinline__ h2 pk2(float x, float y) {
  return __builtin_bit_cast(h2, __builtin_amdgcn_cvt_pkrtz(x, y));
}

template <int CTRL>
__device__ __forceinline__ float dpp_f(float x) {
  int r = __builtin_amdgcn_update_dpp(0, __builtin_bit_cast(int, x), CTRL, 0xF, 0xF, true);
  return __builtin_bit_cast(float, r);
}
__device__ __forceinline__ float rowmax16(float x) {
  x = fmaxf(x, dpp_f<0xB1>(x));    // xor 1
  x = fmaxf(x, dpp_f<0x4E>(x));    // xor 2
  x = fmaxf(x, dpp_f<0x124>(x));   // row_ror:4
  x = fmaxf(x, dpp_f<0x128>(x));   // row_ror:8
  return x;
}

// CH = key-chunk size in KT-tiles; EPB = workspace entries per (b,h)
template <int CH, int EPB>
__global__ __launch_bounds__(256, 3)
void dsattn_fwd(const float* __restrict__ Qg, const float* __restrict__ Kg,
                const float* __restrict__ Vg, const float* __restrict__ taug,
                const float* __restrict__ deltag, float* __restrict__ Og,
                float* __restrict__ Opart, float* __restrict__ Mpart,
                float* __restrict__ Lpart) {
  __shared__ __align__(16) _Float16 Ks[2][KT * LDK];
  __shared__ __align__(16) _Float16 Vt[2][Ec * LDK];
  __shared__ __align__(16) _Float16 Pb[4][16 * LDK];

  const int bx = (int)blockIdx.x;
  int qt, c0;
  if (CH >= NQT) { qt = NQT - 1 - bx; c0 = 0; }
  else { qt = NQT - 1 - (bx >> 2); c0 = bx & 3; if (c0 * CH > qt) return; }
  const int nch = qt / CH + 1;
  const int ktBeg = c0 * CH;
  const int ktEnd = (qt < ktBeg + CH - 1) ? qt : (ktBeg + CH - 1);  // inclusive

  const int tid = threadIdx.x;
  const int wave = tid >> 6, lane = tid & 63;
  const int quad = lane >> 4, l16 = lane & 15;
  const int q0 = qt * QT;
  const int bh = (int)blockIdx.y;
  const int b = bh >> 3, h = bh & 7;

  const float ct = taug[b] * (SCALE * LOG2E);

  // ---- Q A-fragments ----
  const int qm = q0 + (wave << 4) + l16;
  const float* qp = Qg + (((size_t)b * Lc + qm) * Hc + h) * Ec;
  h8 qfrag[2];
#pragma unroll
  for (int kk = 0; kk < 2; ++kk) {
    float4 a0 = ((const float4*)(qp + quad * 8 + kk * 32))[0];
    float4 a1 = ((const float4*)(qp + quad * 8 + kk * 32))[1];
    union { h8 v; h2 p[4]; } u;
    u.p[0] = pk2(a0.x, a0.y); u.p[1] = pk2(a0.z, a0.w);
    u.p[2] = pk2(a1.x, a1.y); u.p[3] = pk2(a1.z, a1.w);
    qfrag[kk] = u.v;
  }

  h8 onesf;
#pragma unroll
  for (int j = 0; j < 8; ++j) onesf[j] = (_Float16)1.0f;

  f32x4 Oacc[4], Osum;
#pragma unroll
  for (int nt = 0; nt < 4; ++nt) Oacc[nt] = (f32x4){0.f, 0.f, 0.f, 0.f};
  Osum = (f32x4){0.f, 0.f, 0.f, 0.f};
  float mrow[4];
#pragma unroll
  for (int r = 0; r < 4; ++r) mrow[r] = -1e30f;

  const int srow = tid >> 2;
  const int sec = (tid & 3) << 4;
  const int vrp = ((tid >> 3) + 4 * (tid & 7)) & 31;
  const int ve8 = (tid & 7) << 3;

  _Float16* pb = &Pb[wave][0];
  float dcur[4];

  // ---- prologue: stage tile ktBeg into buffer 0 ----
  {
    const int kb = ktBeg * KT;
    const float* kp = Kg + (((size_t)b * Sc + kb + srow) * Hc + h) * Ec + sec;
    float4 c0v = ((const float4*)kp)[0], c1v = ((const float4*)kp)[1];
    float4 c2v = ((const float4*)kp)[2], c3v = ((const float4*)kp)[3];
    const float* vp0 = Vg + (((size_t)b * Sc + kb + 2 * vrp) * Hc + h) * Ec + ve8;
    const float* vp1 = vp0 + Hc * Ec;
    float4 r00 = ((const float4*)vp0)[0], r01 = ((const float4*)vp0)[1];
    float4 r10 = ((const float4*)vp1)[0], r11 = ((const float4*)vp1)[1];
#pragma unroll
    for (int nt = 0; nt < 4; ++nt)
      dcur[nt] = deltag[(size_t)b * Sc + kb + nt * 16 + l16] * (SCALE * LOG2E);
    union { h8 v; h2 p[4]; } w0, w1;
    w0.p[0] = pk2(c0v.x, c0v.y); w0.p[1] = pk2(c0v.z, c0v.w);
    w0.p[2] = pk2(c1v.x, c1v.y); w0.p[3] = pk2(c1v.z, c1v.w);
    w1.p[0] = pk2(c2v.x, c2v.y); w1.p[1] = pk2(c2v.z, c2v.w);
    w1.p[2] = pk2(c3v.x, c3v.y); w1.p[3] = pk2(c3v.z, c3v.w);
    *(h8*)&Ks[0][srow * LDK + sec] = w0.v;
    *(h8*)&Ks[0][srow * LDK + sec + 8] = w1.v;
    const float e0[8] = {r00.x, r00.y, r00.z, r00.w, r01.x, r01.y, r01.z, r01.w};
    const float e1[8] = {r10.x, r10.y, r10.z, r10.w, r11.x, r11.y, r11.z, r11.w};
#pragma unroll
    for (int j = 0; j < 8; ++j)
      *(h2*)&Vt[0][(ve8 + j) * LDK + 2 * vrp] = pk2(e0[j], e1[j]);
  }

  for (int kt = ktBeg; kt <= ktEnd; ++kt) {
    const int cur = (kt - ktBeg) & 1;
    const bool pf = (kt < ktEnd);

    float4 kn0, kn1, kn2, kn3, vn00, vn01, vn10, vn11;
    float dn[4];
    if (pf) {
      const int nb = (kt + 1) * KT;
      const float* kp = Kg + (((size_t)b * Sc + nb + srow) * Hc + h) * Ec + sec;
      kn0 = ((const float4*)kp)[0]; kn1 = ((const float4*)kp)[1];
      kn2 = ((const float4*)kp)[2]; kn3 = ((const float4*)kp)[3];
      const float* vp0 = Vg + (((size_t)b * Sc + nb + 2 * vrp) * Hc + h) * Ec + ve8;
      const float* vp1 = vp0 + Hc * Ec;
      vn00 = ((const float4*)vp0)[0]; vn01 = ((const float4*)vp0)[1];
      vn10 = ((const float4*)vp1)[0]; vn11 = ((const float4*)vp1)[1];
#pragma unroll
      for (int nt = 0; nt < 4; ++nt)
        dn[nt] = deltag[(size_t)b * Sc + nb + nt * 16 + l16];
    }

    __syncthreads();

    // ---- S = Q.K^T ----
    f32x4 Sacc[4];
#pragma unroll
    for (int nt = 0; nt < 4; ++nt) Sacc[nt] = (f32x4){0.f, 0.f, 0.f, 0.f};
#pragma unroll
    for (int kk = 0; kk < 2; ++kk) {
#pragma unroll
      for (int nt = 0; nt < 4; ++nt) {
        h8 bf = *(const h8*)&Ks[cur][(nt * 16 + l16) * LDK + quad * 8 + kk * 32];
        Sacc[nt] = __builtin_amdgcn_mfma_f32_16x16x32_f16(qfrag[kk], bf, Sacc[nt], 0, 0, 0);
      }
    }

    const int kbase = kt * KT;
    const int qr0 = q0 + (wave << 4) + (quad << 2);
    const bool diag = (kt == qt);
    float sv[4][4];
#pragma unroll
    for (int nt = 0; nt < 4; ++nt) {
      const int key = kbase + nt * 16 + l16;
#pragma unroll
      for (int r = 0; r < 4; ++r) {
        float s = Sacc[nt][r] * ct + dcur[nt];
        sv[nt][r] = (!diag || key <= qr0 + r) ? s : -1e30f;
      }
    }

    float alpha[4];
#pragma unroll
    for (int r = 0; r < 4; ++r) {
      float t = fmaxf(fmaxf(sv[0][r], sv[1][r]), fmaxf(sv[2][r], sv[3][r]));
      t = rowmax16(t);
      float mn = fmaxf(mrow[r], t);
      alpha[r] = __builtin_amdgcn_exp2f(mrow[r] - mn);
      mrow[r] = mn;
    }
#pragma unroll
    for (int nt = 0; nt < 4; ++nt)
#pragma unroll
      for (int r = 0; r < 4; ++r)
        sv[nt][r] = __builtin_amdgcn_exp2f(sv[nt][r] - mrow[r]);

#pragma unroll
    for (int nt = 0; nt < 4; ++nt)
#pragma unroll
      for (int r = 0; r < 4; ++r) Oacc[nt][r] *= alpha[r];
#pragma unroll
    for (int r = 0; r < 4; ++r) Osum[r] *= alpha[r];

    // ---- P -> per-wave LDS (DPP xor1 pairing, packed h2 writes) ----
    {
      const int lo = l16 & 1;
      const int base = (lo ? 32 : 0) + (l16 & ~1);
#pragma unroll
      for (int r = 0; r < 4; ++r) {
        float o0 = dpp_f<0xB1>(sv[0][r]);
        float o1 = dpp_f<0xB1>(sv[1][r]);
        float o2 = dpp_f<0xB1>(sv[2][r]);
        float o3 = dpp_f<0xB1>(sv[3][r]);
        h2 d0 = pk2(lo ? o2 : sv[0][r], lo ? sv[2][r] : o0);
        h2 d1 = pk2(lo ? o3 : sv[1][r], lo ? sv[3][r] : o1);
        _Float16* pp = &pb[((quad << 2) + r) * LDK + base];
        *(h2*)pp = d0;
        *(h2*)(pp + 16) = d1;
      }
    }
    asm volatile("s_waitcnt lgkmcnt(0)" ::: "memory");

    // ---- O += P.V ; Osum += P.1 ----
#pragma unroll
    for (int kk = 0; kk < 2; ++kk) {
      h8 af = *(const h8*)&pb[l16 * LDK + quad * 8 + kk * 32];
#pragma unroll
      for (int nt = 0; nt < 4; ++nt) {
        h8 vf = *(const h8*)&Vt[cur][(nt * 16 + l16) * LDK + quad * 8 + kk * 32];
        Oacc[nt] = __builtin_amdgcn_mfma_f32_16x16x32_f16(af, vf, Oacc[nt], 0, 0, 0);
      }
      Osum = __builtin_amdgcn_mfma_f32_16x16x32_f16(af, onesf, Osum, 0, 0, 0);
    }

    if (pf) {
      _Float16* ksn = &Ks[cur ^ 1][0];
      _Float16* vtn = &Vt[cur ^ 1][0];
      union { h8 v; h2 p[4]; } w0, w1;
      w0.p[0] = pk2(kn0.x, kn0.y); w0.p[1] = pk2(kn0.z, kn0.w);
      w0.p[2] = pk2(kn1.x, kn1.y); w0.p[3] = pk2(kn1.z, kn1.w);
      w1.p[0] = pk2(kn2.x, kn2.y); w1.p[1] = pk2(kn2.z, kn2.w);
      w1.p[2] = pk2(kn3.x, kn3.y); w1.p[3] = pk2(kn3.z, kn3.w);
      *(h8*)&ksn[srow * LDK + sec] = w0.v;
      *(h8*)&ksn[srow * LDK + sec + 8] = w1.v;
      const float e0[8] = {vn00.x, vn00.y, vn00.z, vn00.w, vn01.x, vn01.y, vn01.z, vn01.w};
      const float e1[8] = {vn10.x, vn10.y, vn10.z, vn10.w, vn11.x, vn11.y, vn11.z, vn11.w};
#pragma unroll
      for (int j = 0; j < 8; ++j)
        *(h2*)&vtn[(ve8 + j) * LDK + 2 * vrp] = pk2(e0[j], e1[j]);
#pragma unroll
      for (int nt = 0; nt < 4; ++nt) dcur[nt] = dn[nt] * (SCALE * LOG2E);
    }
  }

  // ---- epilogue ----
  if (nch == 1) {
#pragma unroll
    for (int r = 0; r < 4; ++r) {
      const int qrow = q0 + (wave << 4) + (quad << 2) + r;
      const float inv = 1.0f / Osum[r];
      float* op = Og + (((size_t)b * Lc + qrow) * Hc + h) * Ec;
#pragma unroll
      for (int nt = 0; nt < 4; ++nt) op[nt * 16 + l16] = Oacc[nt][r] * inv;
    }
  } else {
    // entry index: e = bh*EPB + prefix(qt) + c0 ; prefix = qt + CH*g(g-1)/2 + rem*g
    const int g = qt / CH, rem = qt - g * CH;
    const int pre = qt + CH * (g * (g - 1) / 2) + rem * g;
    const int e = bh * EPB + pre + c0;
    float* op = Opart + (size_t)e * (QT * Ec);
#pragma unroll
    for (int r = 0; r < 4; ++r) {
      const int row = (wave << 4) + (quad << 2) + r;
#pragma unroll
      for (int nt = 0; nt < 4; ++nt)
        op[row * Ec + nt * 16 + l16] = Oacc[nt][r];
      if (l16 == 0) {
        Mpart[e * QT + row] = mrow[r];
        Lpart[e * QT + row] = Osum[r];
      }
    }
  }
}

template <int CH, int EPB>
__global__ __launch_bounds__(256, 4)
void dsattn_comb(const float* __restrict__ Opart, const float* __restrict__ Mpart,
                 const float* __restrict__ Lpart, float* __restrict__ Og) {
  const int qt = CH + (int)blockIdx.x;          // multi-chunk qtiles only
  const int bh = (int)blockIdx.y;
  const int b = bh >> 3, h = bh & 7;
  const int nch = qt / CH + 1;                  // 2..4
  const int row = threadIdx.x >> 2;             // 0..63
  const int colg = (threadIdx.x & 3) << 4;      // 0,16,32,48

  const int g = qt / CH, rem = qt - g * CH;
  const int pre = qt + CH * (g * (g - 1) / 2) + rem * g;
  const int e0 = bh * EPB + pre;

  float ms[4];
  float M = -1e30f;
  for (int c = 0; c < nch; ++c) {
    ms[c] = Mpart[(e0 + c) * QT + row];
    M = fmaxf(M, ms[c]);
  }
  float acc[16];
#pragma unroll
  for (int i = 0; i < 16; ++i) acc[i] = 0.f;
  float l = 0.f;
  for (int c = 0; c < nch; ++c) {
    const float w = __builtin_amdgcn_exp2f(ms[c] - M);
    l += w * Lpart[(e0 + c) * QT + row];
    const float* op = Opart + (size_t)(e0 + c) * (QT * Ec) + row * Ec + colg;
#pragma unroll
    for (int i = 0; i < 4; ++i) {
      float4 v = ((const float4*)op)[i];
      acc[4 * i + 0] += w * v.x; acc[4 * i + 1] += w * v.y;
      acc[4 * i + 2] += w * v.z; acc[4 * i + 3] += w * v.w;
    }
  }
  const float inv = 1.0f / l;
  const int qrow = qt * QT + row;
  float* out = Og + (((size_t)b * Lc + qrow) * Hc + h) * Ec + colg;
#pragma unroll
  for (int i = 0; i < 4; ++i) {
    float4 v;
    v.x = acc[4 * i + 0] * inv; v.y = acc[4 * i + 1] * inv;
    v.z = acc[4 * i + 2] * inv; v.w = acc[4 * i + 3] * inv;
    ((float4*)out)[i] = v;
  }
}

extern "C" void kernel_launch(void* const* d_in, const int* in_sizes, int n_in,
                              void* d_out, int out_size, void* d_ws, size_t ws_size,
                              hipStream_t stream) {
  const float* Q = (const float*)d_in[0];
  const float* K = (const float*)d_in[1];
  const float* V = (const float*)d_in[2];
  const float* tau = (const float*)d_in[3];
  const float* delta = (const float*)d_in[4];
  float* O = (float*)d_out;

  constexpr int CH = 8;                    // 8 KT-tiles = 512 keys per chunk
  constexpr int EPB = 80;                  // prefix(32) for CH=8
  constexpr int TOT_E = Bc * Hc * EPB;     // 1280 entries
  const size_t need = (size_t)TOT_E * QT * Ec * 4 + 2 * (size_t)TOT_E * QT * 4;

  if (ws_size >= need) {
    float* Opart = (float*)d_ws;
    float* Mpart = Opart + (size_t)TOT_E * QT * Ec;
    float* Lpart = Mpart + (size_t)TOT_E * QT;
    dim3 g1(NQT * 4, Bc * Hc);             // 4 = max chunks per qtile
    dsattn_fwd<CH, EPB><<<g1, 256, 0, stream>>>(Q, K, V, tau, delta, O,
                                                Opart, Mpart, Lpart);
    dim3 g2(NQT - CH, Bc * Hc);            // multi-chunk qtiles
    dsattn_comb<CH, EPB><<<g2, 256, 0, stream>>>(Opart, Mpart, Lpart, O);
  } else {
    // fallback: monolithic (no workspace use)
    dim3 g1(NQT, Bc * Hc);
    dsattn_fwd<NQT, NQT><<<g1, 256, 0, stream>>>(Q, K, V, tau, delta, O,
                                                 nullptr, nullptr, nullptr);
  }
}